// Round 1
// baseline (223.239 us; speedup 1.0000x reference)
//
#include <hip/hip_runtime.h>
#include <hip/hip_bf16.h>
#include <math.h>

namespace {
constexpr int kB = 2;
constexpr int kT = 4096;
constexpr int kD = 512;
constexpr int kH = 64;
constexpr int kCW = 256;
}

// ---------------------------------------------------------------------------
// Kernel A: Q/K/V projection. One block per token row (B*T rows).
// X row staged in LDS; threads 0..191 each compute one output element
// (m = which matrix, h = head dim) via a 512-MAC dot product.
// ---------------------------------------------------------------------------
__global__ __launch_bounds__(256) void qkv_proj(const float* __restrict__ X,
                                                const float* __restrict__ Wq,
                                                const float* __restrict__ Wk,
                                                const float* __restrict__ Wv,
                                                float* __restrict__ QKV) {
  __shared__ float xs[kD];
  const int row = blockIdx.x;  // 0 .. kB*kT-1
  const float* xrow = X + (size_t)row * kD;
  for (int i = threadIdx.x; i < kD; i += 256) xs[i] = xrow[i];
  __syncthreads();

  const int tid = threadIdx.x;
  if (tid < 192) {
    const int m = tid >> 6;   // 0=Q, 1=K, 2=V
    const int h = tid & 63;
    const float* W = (m == 0) ? Wq : (m == 1) ? Wk : Wv;
    float acc = 0.f;
#pragma unroll 16
    for (int d = 0; d < kD; ++d) acc += xs[d] * W[d * kH + h];
    // QKV layout: [3][B*T][H]
    QKV[((size_t)m * kB * kT + row) * kH + h] = acc;
  }
}

// ---------------------------------------------------------------------------
// Kernel B: sliding-window attention for one (b, t) per block.
// Reproduces the reference's padding semantics exactly:
//   score_j = (Q[t] . K[t+j-255]) / 8   if t+j-255 >= 0
//           = 0                         if t+j-255 < 0   (zero-pad key)
//           masked to -inf              if j > t
// out[t]  = sum_j softmax(score)_j * V[t+j-255]   (V zero-padded)
// ---------------------------------------------------------------------------
__global__ __launch_bounds__(256) void swin_attn(const float* __restrict__ Q,
                                                 const float* __restrict__ K,
                                                 const float* __restrict__ V,
                                                 float* __restrict__ O) {
  const int row = blockIdx.x;  // b*T + t
  const int t = row % kT;
  const int b = row / kT;

  __shared__ float qs[kH];
  __shared__ float p[kCW];
  __shared__ float red[8];
  __shared__ float oacc[4][kH];

  const int tid = threadIdx.x;
  if (tid < kH) qs[tid] = Q[(size_t)row * kH + tid];
  __syncthreads();

  // ---- scores: thread j handles window slot j ----
  const int j = tid;
  const int kidx = t + j - (kCW - 1);
  float s;
  if (j > t) {
    s = -INFINITY;
  } else if (kidx < 0) {
    s = 0.f;  // zero-pad key: dot product is exactly 0
  } else {
    const float* krow = K + ((size_t)b * kT + kidx) * kH;
    float acc = 0.f;
#pragma unroll
    for (int h = 0; h < kH; ++h) acc += qs[h] * krow[h];
    s = acc * 0.125f;  // 1/sqrt(H)
  }

  // ---- block max (64-lane shuffle butterfly, then 4 wave partials) ----
  float m = s;
#pragma unroll
  for (int off = 32; off > 0; off >>= 1) m = fmaxf(m, __shfl_xor(m, off));
  if ((tid & 63) == 0) red[tid >> 6] = m;
  __syncthreads();
  if (tid == 0) red[4] = fmaxf(fmaxf(red[0], red[1]), fmaxf(red[2], red[3]));
  __syncthreads();
  m = red[4];

  // ---- exp + block sum ----
  const float e = expf(s - m);  // s = -inf -> 0
  float sum = e;
#pragma unroll
  for (int off = 32; off > 0; off >>= 1) sum += __shfl_xor(sum, off);
  if ((tid & 63) == 0) red[tid >> 6] = sum;
  __syncthreads();
  if (tid == 0) red[4] = (red[0] + red[1]) + (red[2] + red[3]);
  __syncthreads();
  const float denom = red[4];
  p[j] = e / denom;
  __syncthreads();

  // ---- PV: 4 waves split the j-range; lane = head dim h (coalesced V) ----
  const int wave = tid >> 6;
  const int lane = tid & 63;
  const int jlo = max(0, (kCW - 1) - t);     // below this, V is zero-pad
  const int jhi = min(kCW - 1, t);           // above this, p == 0
  const int lo = max(jlo, wave * 64);
  const int hi = min(jhi, wave * 64 + 63);
  const float* vb = V + (size_t)b * kT * kH + lane;
  float acc = 0.f;
  for (int jj = lo; jj <= hi; ++jj) {
    acc += p[jj] * vb[(t + jj - (kCW - 1)) * kH];
  }
  oacc[wave][lane] = acc;
  __syncthreads();
  if (tid < kH) {
    O[(size_t)row * kH + tid] =
        (oacc[0][tid] + oacc[1][tid]) + (oacc[2][tid] + oacc[3][tid]);
  }
}

// ---------------------------------------------------------------------------
extern "C" void kernel_launch(void* const* d_in, const int* in_sizes, int n_in,
                              void* d_out, int out_size, void* d_ws, size_t ws_size,
                              hipStream_t stream) {
  const float* X  = (const float*)d_in[0];
  const float* Wq = (const float*)d_in[1];
  const float* Wk = (const float*)d_in[2];
  const float* Wv = (const float*)d_in[3];
  float* QKV = (float*)d_ws;  // [3][B*T][H] f32 = 6.29 MB
  float* O = (float*)d_out;

  const int rows = kB * kT;
  qkv_proj<<<rows, 256, 0, stream>>>(X, Wq, Wk, Wv, QKV);

  const float* Qp = QKV;
  const float* Kp = QKV + (size_t)rows * kH;
  const float* Vp = QKV + 2 * (size_t)rows * kH;
  swin_attn<<<rows, 256, 0, stream>>>(Qp, Kp, Vp, O);
}

// Round 2
// 169.702 us; speedup vs baseline: 1.3155x; 1.3155x over previous
//
#include <hip/hip_runtime.h>
#include <hip/hip_bf16.h>
#include <math.h>

namespace {
constexpr int kB = 2;
constexpr int kT = 4096;
constexpr int kD = 512;
constexpr int kH = 64;
constexpr int kCW = 256;
constexpr int kRows = kB * kT;
constexpr int kRB = 16;  // rows per qkv block
}

// ---------------------------------------------------------------------------
// Kernel A: Q/K/V projection, 16 rows per block.
// Thread (m,h) keeps 16 accumulators; each W element loaded once feeds 16
// FMAs -> W L2 traffic drops 16x (was the 34 TB/s L2-BW bottleneck).
// X addresses are wave-uniform -> scalar loads.
// K is written TRANSPOSED (KT[b][h][t]) so the attention QK pass can read it
// coalesced (lane = window slot j -> consecutive t).
// ---------------------------------------------------------------------------
__global__ __launch_bounds__(192) void qkv_proj(const float* __restrict__ X,
                                                const float* __restrict__ Wq,
                                                const float* __restrict__ Wk,
                                                const float* __restrict__ Wv,
                                                float* __restrict__ Qo,
                                                float* __restrict__ KT,
                                                float* __restrict__ Vo) {
  const int row0 = blockIdx.x * kRB;
  const int tid = threadIdx.x;
  const int m = tid >> 6;  // 0=Q, 1=K, 2=V (one wave each)
  const int h = tid & 63;
  const float* __restrict__ W = (m == 0) ? Wq : (m == 1) ? Wk : Wv;

  float acc[kRB];
#pragma unroll
  for (int r = 0; r < kRB; ++r) acc[r] = 0.f;

  const float* __restrict__ xbase = X + (size_t)row0 * kD;
  for (int d = 0; d < kD; d += 4) {
    const float w0 = W[(d + 0) * kH + h];
    const float w1 = W[(d + 1) * kH + h];
    const float w2 = W[(d + 2) * kH + h];
    const float w3 = W[(d + 3) * kH + h];
#pragma unroll
    for (int r = 0; r < kRB; ++r) {
      const float4 x = *reinterpret_cast<const float4*>(xbase + (size_t)r * kD + d);
      acc[r] = fmaf(x.w, w3, fmaf(x.z, w2, fmaf(x.y, w1, fmaf(x.x, w0, acc[r]))));
    }
  }

  if (m == 1) {
    // K transposed: KT[(b*64 + h)*T + t], 16 consecutive t per thread.
    const int b = row0 >> 12;
    const int t0 = row0 & (kT - 1);
    float* kt = KT + ((size_t)(b * kH + h)) * kT + t0;
#pragma unroll
    for (int rq = 0; rq < kRB / 4; ++rq) {
      float4 v;
      v.x = acc[4 * rq + 0];
      v.y = acc[4 * rq + 1];
      v.z = acc[4 * rq + 2];
      v.w = acc[4 * rq + 3];
      *reinterpret_cast<float4*>(kt + 4 * rq) = v;
    }
  } else {
    float* out = (m == 0) ? Qo : Vo;
#pragma unroll
    for (int r = 0; r < kRB; ++r) out[(size_t)(row0 + r) * kH + h] = acc[r];
  }
}

// ---------------------------------------------------------------------------
// Kernel B: sliding-window attention, one (b,t) per block.
// QK now reads K via KT[b][h][t-255+j]: lane j -> consecutive addresses,
// coalesced (was 64 cache lines per load instruction).
// Padding semantics identical to the reference:
//   score_j = 0 for zero-pad keys (kidx<0), -inf for j>t.
// ---------------------------------------------------------------------------
__global__ __launch_bounds__(256) void swin_attn(const float* __restrict__ Q,
                                                 const float* __restrict__ KT,
                                                 const float* __restrict__ V,
                                                 float* __restrict__ O) {
  const int row = blockIdx.x;  // b*T + t
  const int t = row & (kT - 1);
  const int b = row >> 12;

  __shared__ float qs[kH];
  __shared__ float p[kCW];
  __shared__ float red[8];
  __shared__ float oacc[4][kH];

  const int tid = threadIdx.x;
  if (tid < kH) qs[tid] = Q[(size_t)row * kH + tid];
  __syncthreads();

  // ---- scores ----
  const int j = tid;
  const int kidx = t + j - (kCW - 1);
  float s;
  if (j > t) {
    s = -INFINITY;
  } else if (kidx < 0) {
    s = 0.f;  // zero-pad key
  } else {
    const float* kcol = KT + (size_t)b * kH * kT + kidx;
    float a = 0.f;
#pragma unroll
    for (int hh = 0; hh < kH; ++hh) a = fmaf(qs[hh], kcol[(size_t)hh * kT], a);
    s = a * 0.125f;
  }

  // ---- block max ----
  float m = s;
#pragma unroll
  for (int off = 32; off > 0; off >>= 1) m = fmaxf(m, __shfl_xor(m, off));
  if ((tid & 63) == 0) red[tid >> 6] = m;
  __syncthreads();
  if (tid == 0) red[4] = fmaxf(fmaxf(red[0], red[1]), fmaxf(red[2], red[3]));
  __syncthreads();
  m = red[4];

  // ---- exp + block sum ----
  const float e = (s == -INFINITY) ? 0.f : __expf(s - m);
  float sum = e;
#pragma unroll
  for (int off = 32; off > 0; off >>= 1) sum += __shfl_xor(sum, off);
  if ((tid & 63) == 0) red[tid >> 6] = sum;
  __syncthreads();
  if (tid == 0) red[4] = (red[0] + red[1]) + (red[2] + red[3]);
  __syncthreads();
  p[j] = e / red[4];
  __syncthreads();

  // ---- PV: 4 waves split the window; lane = head dim (coalesced V) ----
  const int wave = tid >> 6;
  const int lane = tid & 63;
  const int jlo = max(0, (kCW - 1) - t);
  const int jhi = min(kCW - 1, t);
  const int lo = max(jlo, wave * 64);
  const int hi = min(jhi, wave * 64 + 63);
  const float* vb = V + (size_t)b * kT * kH + lane;
  float acc = 0.f;
  for (int jj = lo; jj <= hi; ++jj) {
    acc += p[jj] * vb[(size_t)(t + jj - (kCW - 1)) * kH];
  }
  oacc[wave][lane] = acc;
  __syncthreads();
  if (tid < kH) {
    O[(size_t)row * kH + tid] =
        (oacc[0][tid] + oacc[1][tid]) + (oacc[2][tid] + oacc[3][tid]);
  }
}

// ---------------------------------------------------------------------------
extern "C" void kernel_launch(void* const* d_in, const int* in_sizes, int n_in,
                              void* d_out, int out_size, void* d_ws, size_t ws_size,
                              hipStream_t stream) {
  const float* X  = (const float*)d_in[0];
  const float* Wq = (const float*)d_in[1];
  const float* Wk = (const float*)d_in[2];
  const float* Wv = (const float*)d_in[3];
  float* Qo = (float*)d_ws;                        // [B*T][H]
  float* KT = Qo + (size_t)kRows * kH;             // [B][H][T] transposed
  float* Vo = KT + (size_t)kRows * kH;             // [B*T][H]
  float* O = (float*)d_out;

  qkv_proj<<<kRows / kRB, 192, 0, stream>>>(X, Wq, Wk, Wv, Qo, KT, Vo);
  swin_attn<<<kRows, 256, 0, stream>>>(Qo, KT, Vo, O);
}

// Round 3
// 113.053 us; speedup vs baseline: 1.9746x; 1.5011x over previous
//
#include <hip/hip_runtime.h>
#include <math.h>

namespace {
constexpr int kB = 2;
constexpr int kT = 4096;
constexpr int kD = 512;
constexpr int kH = 64;
constexpr int kRows = kB * kT;
constexpr int kRB = 8;    // rows per qkv block
constexpr int TQ = 16;    // queries per attn block
constexpr int NCH = 5;    // K/V chunks of 64 covering [t0-256, t0+63]
constexpr int CHS = 64;   // chunk size
constexpr int KVPAD = 68; // LDS row pad (f32 words), 272B rows: 16B-aligned
}

// ---------------------------------------------------------------------------
// Kernel A: Q/K/V projection. kRB=8 rows/block, 1024 blocks x 3 waves.
// Wave m computes matrix m; each W element feeds 8 FMAs (register row-block).
// All outputs row-major [B*T][H].
// ---------------------------------------------------------------------------
__global__ __launch_bounds__(192) void qkv_proj(const float* __restrict__ X,
                                                const float* __restrict__ Wq,
                                                const float* __restrict__ Wk,
                                                const float* __restrict__ Wv,
                                                float* __restrict__ Qo,
                                                float* __restrict__ Ko,
                                                float* __restrict__ Vo) {
  const int row0 = blockIdx.x * kRB;
  const int tid = threadIdx.x;
  const int m = tid >> 6;
  const int h = tid & 63;
  const float* __restrict__ W = (m == 0) ? Wq : (m == 1) ? Wk : Wv;

  float acc[kRB];
#pragma unroll
  for (int r = 0; r < kRB; ++r) acc[r] = 0.f;

  const float* __restrict__ xbase = X + (size_t)row0 * kD;
  for (int d = 0; d < kD; d += 4) {
    const float w0 = W[(d + 0) * kH + h];
    const float w1 = W[(d + 1) * kH + h];
    const float w2 = W[(d + 2) * kH + h];
    const float w3 = W[(d + 3) * kH + h];
#pragma unroll
    for (int r = 0; r < kRB; ++r) {
      const float4 x = *reinterpret_cast<const float4*>(xbase + (size_t)r * kD + d);
      acc[r] = fmaf(x.w, w3, fmaf(x.z, w2, fmaf(x.y, w1, fmaf(x.x, w0, acc[r]))));
    }
  }

  float* __restrict__ out = (m == 0) ? Qo : (m == 1) ? Ko : Vo;
#pragma unroll
  for (int r = 0; r < kRB; ++r) out[(size_t)(row0 + r) * kH + h] = acc[r];
}

// ---------------------------------------------------------------------------
// Kernel B: sliding-window attention, 16 queries per block, LDS-staged K/V.
// Scores S[i][jg], jg in [0,320) maps to key position p = t0-256+jg.
// Reference semantics: window slot j = p - t + 255 valid iff p>=0, 0<=j<=255,
// j<=t. Zero-pad slots (kidx<0, j<=t) handled analytically:
//   n0 = (t<255) ? min(t+1, 255-t) : 0 slots, each contributing exp(-m)
//   to the denominator and 0 to PV.
// ---------------------------------------------------------------------------
__global__ __launch_bounds__(256) void swin_attn(const float* __restrict__ Q,
                                                 const float* __restrict__ K,
                                                 const float* __restrict__ V,
                                                 float* __restrict__ O) {
  __shared__ float Qs[TQ][KVPAD];
  __shared__ float Sm[TQ][NCH * CHS];
  __shared__ float KV[CHS][KVPAD];

  const int tid = threadIdx.x;
  const int row0 = blockIdx.x * TQ;
  const int t0 = row0 & (kT - 1);
  const int b = row0 >> 12;
  const float* __restrict__ Kb = K + (size_t)b * kT * kH;
  const float* __restrict__ Vb = V + (size_t)b * kT * kH;

  // stage Q tile (one float4 per thread)
  {
    const int r = tid >> 4;
    const int h4 = (tid & 15) * 4;
    *reinterpret_cast<float4*>(&Qs[r][h4]) =
        *reinterpret_cast<const float4*>(&Q[(size_t)(row0 + r) * kH + h4]);
  }

  const int w = tid >> 6;
  const int lane = tid & 63;
  const int i0 = 4 * w;
  const int tmin = t0 + i0;      // first query this wave owns
  const int tmax = t0 + i0 + 3;  // last

  // ---- Phase A: scores ----
  for (int c = 0; c < NCH; ++c) {
    const int p0 = t0 - 256 + c * CHS;
    __syncthreads();  // previous compute done before overwriting KV
    for (int f = tid; f < CHS * kH / 4; f += 256) {
      const int r = f >> 4;
      const int h4 = (f & 15) * 4;
      const int p = p0 + r;
      float4 v = make_float4(0.f, 0.f, 0.f, 0.f);
      if (p >= 0 && p < kT)
        v = *reinterpret_cast<const float4*>(&Kb[(size_t)p * kH + h4]);
      *reinterpret_cast<float4*>(&KV[r][h4]) = v;
    }
    __syncthreads();

    const int lo = max(0, max(0, tmin - 255) - p0);
    const int hi = min(CHS - 1, tmax - p0);
    if (lo <= hi && lane >= lo && lane <= hi) {
      float s0 = 0.f, s1 = 0.f, s2 = 0.f, s3 = 0.f;
#pragma unroll
      for (int h0 = 0; h0 < kH; h0 += 4) {
        const float4 kv4 = *reinterpret_cast<const float4*>(&KV[lane][h0]);
        const float4 q0 = *reinterpret_cast<const float4*>(&Qs[i0 + 0][h0]);
        const float4 q1 = *reinterpret_cast<const float4*>(&Qs[i0 + 1][h0]);
        const float4 q2 = *reinterpret_cast<const float4*>(&Qs[i0 + 2][h0]);
        const float4 q3 = *reinterpret_cast<const float4*>(&Qs[i0 + 3][h0]);
        s0 = fmaf(kv4.w, q0.w, fmaf(kv4.z, q0.z, fmaf(kv4.y, q0.y, fmaf(kv4.x, q0.x, s0))));
        s1 = fmaf(kv4.w, q1.w, fmaf(kv4.z, q1.z, fmaf(kv4.y, q1.y, fmaf(kv4.x, q1.x, s1))));
        s2 = fmaf(kv4.w, q2.w, fmaf(kv4.z, q2.z, fmaf(kv4.y, q2.y, fmaf(kv4.x, q2.x, s2))));
        s3 = fmaf(kv4.w, q3.w, fmaf(kv4.z, q3.z, fmaf(kv4.y, q3.y, fmaf(kv4.x, q3.x, s3))));
      }
      const int jg = c * CHS + lane;
      Sm[i0 + 0][jg] = s0 * 0.125f;
      Sm[i0 + 1][jg] = s1 * 0.125f;
      Sm[i0 + 2][jg] = s2 * 0.125f;
      Sm[i0 + 3][jg] = s3 * 0.125f;
    }
  }
  __syncthreads();

  // ---- softmax: 16 lanes per query ----
  {
    const int i = tid >> 4;
    const int l = tid & 15;
    const int t = t0 + i;
    float sv[20];
    float mx = -INFINITY;
#pragma unroll
    for (int k2 = 0; k2 < 20; ++k2) {
      const int jg = l + 16 * k2;
      const int p = t0 - 256 + jg;
      const int jref = p - t + 255;
      const bool valid = (p >= 0) && (jref >= 0) && (jref <= 255) && (jref <= t);
      sv[k2] = valid ? Sm[i][jg] : -INFINITY;
      mx = fmaxf(mx, sv[k2]);
    }
#pragma unroll
    for (int off = 1; off < 16; off <<= 1) mx = fmaxf(mx, __shfl_xor(mx, off));
    const int n0 = (t < 255) ? min(t + 1, 255 - t) : 0;
    if (n0 > 0) mx = fmaxf(mx, 0.f);

    float sum = 0.f;
    float ev[20];
#pragma unroll
    for (int k2 = 0; k2 < 20; ++k2) {
      ev[k2] = (sv[k2] > -INFINITY) ? __expf(sv[k2] - mx) : 0.f;
      sum += ev[k2];
    }
#pragma unroll
    for (int off = 1; off < 16; off <<= 1) sum += __shfl_xor(sum, off);
    sum += (float)n0 * __expf(-mx);
    const float inv = 1.f / sum;
#pragma unroll
    for (int k2 = 0; k2 < 20; ++k2) Sm[i][l + 16 * k2] = ev[k2] * inv;
  }
  // (barrier inside phase-B loop orders these writes before reads)

  // ---- Phase B: PV ----
  float a0 = 0.f, a1 = 0.f, a2 = 0.f, a3 = 0.f;
  const int h = lane;
  for (int c = 0; c < NCH; ++c) {
    const int p0 = t0 - 256 + c * CHS;
    __syncthreads();
    for (int f = tid; f < CHS * kH / 4; f += 256) {
      const int r = f >> 4;
      const int h4 = (f & 15) * 4;
      const int p = p0 + r;
      float4 v = make_float4(0.f, 0.f, 0.f, 0.f);
      if (p >= 0 && p < kT)
        v = *reinterpret_cast<const float4*>(&Vb[(size_t)p * kH + h4]);
      *reinterpret_cast<float4*>(&KV[r][h4]) = v;
    }
    __syncthreads();

    const int lo = max(0, max(0, tmin - 255) - p0);
    const int hi = min(CHS - 1, tmax - p0);
    for (int q = lo; q <= hi; ++q) {
      const int jg = c * CHS + q;
      const float pv0 = Sm[i0 + 0][jg];
      const float pv1 = Sm[i0 + 1][jg];
      const float pv2 = Sm[i0 + 2][jg];
      const float pv3 = Sm[i0 + 3][jg];
      const float vv = KV[q][h];
      a0 = fmaf(pv0, vv, a0);
      a1 = fmaf(pv1, vv, a1);
      a2 = fmaf(pv2, vv, a2);
      a3 = fmaf(pv3, vv, a3);
    }
  }

  O[(size_t)(row0 + i0 + 0) * kH + h] = a0;
  O[(size_t)(row0 + i0 + 1) * kH + h] = a1;
  O[(size_t)(row0 + i0 + 2) * kH + h] = a2;
  O[(size_t)(row0 + i0 + 3) * kH + h] = a3;
}

// ---------------------------------------------------------------------------
extern "C" void kernel_launch(void* const* d_in, const int* in_sizes, int n_in,
                              void* d_out, int out_size, void* d_ws, size_t ws_size,
                              hipStream_t stream) {
  const float* X  = (const float*)d_in[0];
  const float* Wq = (const float*)d_in[1];
  const float* Wk = (const float*)d_in[2];
  const float* Wv = (const float*)d_in[3];
  float* Qo = (float*)d_ws;                 // [B*T][H]
  float* Ko = Qo + (size_t)kRows * kH;      // [B*T][H]
  float* Vo = Ko + (size_t)kRows * kH;      // [B*T][H]
  float* O = (float*)d_out;

  qkv_proj<<<kRows / kRB, 192, 0, stream>>>(X, Wq, Wk, Wv, Qo, Ko, Vo);
  swin_attn<<<kRows / TQ, 256, 0, stream>>>(Qo, Ko, Vo, O);
}